// Round 2
// baseline (913.007 us; speedup 1.0000x reference)
//
#include <hip/hip_runtime.h>
#include <hip/hip_bf16.h>

// Decision-tree traversal, one thread per sample.
// x:      [N, W] int32 binary features (row-major), N=250000, W=784
// choices:[N_NODES] int32 split-feature per node (256 KB, L2-resident)
// preds:  [N_NODES] float32 leaf prediction (0.0/1.0)
// depth:  scalar int32 on device (=15)
// out:    [N] int32 (bool semantics: 0 / 1) -- harness maps bool -> int32
__global__ __launch_bounds__(256) void Tree_17867063951635_kernel(
    const int* __restrict__ x,
    const int* __restrict__ choices,
    const float* __restrict__ preds,
    const int* __restrict__ depth_p,
    int* __restrict__ out,
    int n, int w)
{
    const int i = blockIdx.x * blockDim.x + threadIdx.x;
    if (i >= n) return;

    const int depth = *depth_p;                      // uniform scalar
    const int* __restrict__ row = x + (long long)i * (long long)w;

    int node = 0;
    for (int d = 0; d < depth; ++d) {
        const int c   = choices[node];               // L2-resident table
        const int bit = row[c];                      // HBM gather (4B from own row)
        node = node * 2 + bit + 1;
    }
    out[i] = (preds[node] != 0.0f) ? 1 : 0;          // bool as int32
}

extern "C" void kernel_launch(void* const* d_in, const int* in_sizes, int n_in,
                              void* d_out, int out_size, void* d_ws, size_t ws_size,
                              hipStream_t stream) {
    const int*   x       = (const int*)d_in[0];
    const int*   choices = (const int*)d_in[1];
    const float* preds   = (const float*)d_in[2];
    const int*   depth_p = (const int*)d_in[3];
    int*         out     = (int*)d_out;

    const int n = out_size;                 // 250000 samples
    const int w = in_sizes[0] / n;          // 784 features

    const int block = 256;
    const int grid  = (n + block - 1) / block;
    Tree_17867063951635_kernel<<<grid, block, 0, stream>>>(
        x, choices, preds, depth_p, out, n, w);
}